// Round 8
// baseline (283.337 us; speedup 1.0000x reference)
//
#include <hip/hip_runtime.h>
#include <cstdint>
#include <cstddef>

#define NN   50000
#define EEN  800000
#define INF_ 256
#define HH   3
#define FEAT 192   // H*D
#define EFD  64
#define NEG_ 0.2f
#define EPSF 1e-12f
#define SMASK 0x0FFFFFF0   // s*16 field in srcP
#define NB   ((NN + 1023) / 1024)

typedef __attribute__((ext_vector_type(8))) short short8;
typedef __attribute__((ext_vector_type(4))) float f32x4;

static __device__ __forceinline__ float4 ld4(const float* p) {
    return *reinterpret_cast<const float4*>(p);
}
static __device__ __forceinline__ uint f2b(float f) {
    union { float f; uint32_t u; } v; v.f = f;
    uint32_t u = v.u;
    return (u + 0x7FFFu + ((u >> 16) & 1u)) >> 16;
}
static __device__ __forceinline__ uint pack2(float a, float b) {
    return f2b(a) | (f2b(b) << 16);
}
static __device__ __forceinline__ float blo(uint u) {
    return __uint_as_float(u << 16);
}
static __device__ __forceinline__ float bhi(uint u) {
    return __uint_as_float(u & 0xFFFF0000u);
}

// ---------------- LDS-tiled weight transpose+convert -------------------------
// W[K][N] f32 -> BT[N][K] bf16, all dims multiples of 32
static __device__ __forceinline__ void trans_tile(const float* __restrict__ W,
        ushort* __restrict__ BT, int K, int N, int kt, int nt)
{
    __shared__ float tile[32][33];
    const int tx = threadIdx.x & 31, ty = threadIdx.x >> 5;  // 32 x 8
    #pragma unroll
    for (int r = 0; r < 4; ++r) {
        int row = kt * 32 + ty + r * 8;
        int col = nt * 32 + tx;
        tile[ty + r * 8][tx] = W[(size_t)row * N + col];
    }
    __syncthreads();
    #pragma unroll
    for (int r = 0; r < 4; ++r) {
        int n = nt * 32 + ty + r * 8;
        int k = kt * 32 + tx;
        BT[(size_t)n * K + k] = (ushort)f2b(tile[tx][ty + r * 8]);
    }
}

__global__ __launch_bounds__(256) void k_wtrans3(const float* __restrict__ W1,
        ushort* __restrict__ o1, const float* __restrict__ W2,
        ushort* __restrict__ o2, const float* __restrict__ W3,
        ushort* __restrict__ o3)
{
    int b = blockIdx.x;
    if (b < 48) {            // W1: K=256 (8 ktiles) x N=192 (6 ntiles)
        trans_tile(W1, o1, INF_, FEAT, b >> 3 == 0 ? b & 7 : b & 7, b >> 3);
    } else if (b < 84) {     // W2: 6 x 6
        int i = b - 48;
        trans_tile(W2, o2, FEAT, FEAT, i % 6, i / 6);
    } else {                 // W3: 6 x 6
        int i = b - 84;
        trans_tile(W3, o3, FEAT, FEAT, i % 6, i / 6);
    }
}

// ---------------- GEMM1: 128-row tile, full-N(192), fused el/er --------------
#define LDA 40   // padded LDS row stride (ushort)
__global__ __launch_bounds__(256) void gemm_mfma1(const float* __restrict__ A,
        const ushort* __restrict__ BT, ushort* __restrict__ Cb,
        float4* __restrict__ el4, float4* __restrict__ er4,
        const float* __restrict__ al, const float* __restrict__ ar,
        int M, int K)
{
    __shared__ ushort As[128 * LDA];
    __shared__ ushort Bs[192 * LDA];
    const int t = threadIdx.x;
    const int lane = t & 63, w = t >> 6;
    const int bm = blockIdx.x * 128;
    const int fr = lane & 15;
    const int fq = lane >> 4;
    const int fg = fq * 8;
    const int arow = t >> 1;           // 0..127
    const int acol = (t & 1) * 8;      // 0 or 8 (plus +16 later)
    const int brow = t >> 2;           // 0..63
    const int bcol = (t & 3) * 8;

    f32x4 acc[2][12];
    #pragma unroll
    for (int i = 0; i < 2; ++i)
        #pragma unroll
        for (int c = 0; c < 12; ++c)
            acc[i][c] = (f32x4){0.f, 0.f, 0.f, 0.f};

    const int ga = bm + arow;
    for (int k0 = 0; k0 < K; k0 += 32) {
        uint4 u0 = make_uint4(0,0,0,0), u1 = u0;
        if (ga < M) {
            const float* ap = A + (size_t)ga * K + k0 + acol;
            float4 f0 = ld4(ap), f1 = ld4(ap + 4);
            float4 f2v = ld4(ap + 16), f3 = ld4(ap + 20);
            u0 = make_uint4(pack2(f0.x,f0.y), pack2(f0.z,f0.w),
                            pack2(f1.x,f1.y), pack2(f1.z,f1.w));
            u1 = make_uint4(pack2(f2v.x,f2v.y), pack2(f2v.z,f2v.w),
                            pack2(f3.x,f3.y), pack2(f3.z,f3.w));
        }
        *reinterpret_cast<uint4*>(As + arow * LDA + acol) = u0;
        *reinterpret_cast<uint4*>(As + arow * LDA + acol + 16) = u1;
        #pragma unroll
        for (int j = 0; j < 3; ++j) {
            uint4 bv = *reinterpret_cast<const uint4*>(BT + (size_t)(j * 64 + brow) * K + k0 + bcol);
            *reinterpret_cast<uint4*>(Bs + (j * 64 + brow) * LDA + bcol) = bv;
        }
        __syncthreads();
        short8 afr0 = *reinterpret_cast<const short8*>(As + (w * 32 + fr) * LDA + fg);
        short8 afr1 = *reinterpret_cast<const short8*>(As + (w * 32 + 16 + fr) * LDA + fg);
        #pragma unroll
        for (int c = 0; c < 12; ++c) {
            short8 bfr = *reinterpret_cast<const short8*>(Bs + (c * 16 + fr) * LDA + fg);
            acc[0][c] = __builtin_amdgcn_mfma_f32_16x16x32_bf16(afr0, bfr, acc[0][c], 0, 0, 0);
            acc[1][c] = __builtin_amdgcn_mfma_f32_16x16x32_bf16(afr1, bfr, acc[1][c], 0, 0, 0);
        }
        __syncthreads();
    }
    #pragma unroll
    for (int i = 0; i < 2; ++i) {
        #pragma unroll
        for (int j = 0; j < 4; ++j) {
            int row = bm + w * 32 + i * 16 + fq * 4 + j;
            if (row < M) {
                #pragma unroll
                for (int c = 0; c < 12; ++c)
                    Cb[(size_t)row * FEAT + c * 16 + fr] = (ushort)f2b(acc[i][c][j]);
            }
        }
    }
    float alv[12], arv[12];
    #pragma unroll
    for (int c = 0; c < 12; ++c) {
        alv[c] = al[c * 16 + fr];
        arv[c] = ar[c * 16 + fr];
    }
    #pragma unroll
    for (int i = 0; i < 2; ++i) {
        #pragma unroll
        for (int j = 0; j < 4; ++j) {
            int row = bm + w * 32 + i * 16 + fq * 4 + j;
            float pl0 = 0.f, pl1 = 0.f, pl2 = 0.f;
            float pr0 = 0.f, pr1 = 0.f, pr2 = 0.f;
            #pragma unroll
            for (int c = 0; c < 4; ++c)  { pl0 += acc[i][c][j]*alv[c];  pr0 += acc[i][c][j]*arv[c]; }
            #pragma unroll
            for (int c = 4; c < 8; ++c)  { pl1 += acc[i][c][j]*alv[c];  pr1 += acc[i][c][j]*arv[c]; }
            #pragma unroll
            for (int c = 8; c < 12; ++c) { pl2 += acc[i][c][j]*alv[c];  pr2 += acc[i][c][j]*arv[c]; }
            #pragma unroll
            for (int o = 1; o < 16; o <<= 1) {
                pl0 += __shfl_xor(pl0, o); pl1 += __shfl_xor(pl1, o); pl2 += __shfl_xor(pl2, o);
                pr0 += __shfl_xor(pr0, o); pr1 += __shfl_xor(pr1, o); pr2 += __shfl_xor(pr2, o);
            }
            if (fr == 0 && row < M) {
                el4[row] = make_float4(pl0, pl1, pl2, 0.f);
                er4[row] = make_float4(pr0, pr1, pr2, 0.f);
            }
        }
    }
}

// ---------------- GEMM2: 64-row tile, dual-B, fused el/er --------------------
__global__ __launch_bounds__(256) void gemm_mfma2(const ushort* __restrict__ A,
        const ushort* __restrict__ BT, const ushort* __restrict__ BT2,
        ushort* __restrict__ Cb, ushort* __restrict__ resb,
        float4* __restrict__ el4, float4* __restrict__ er4,
        const float* __restrict__ al, const float* __restrict__ ar,
        int M, int K)
{
    __shared__ ushort As[64 * LDA];
    __shared__ ushort Bs[192 * LDA];
    __shared__ ushort Bs2[192 * LDA];
    const int t = threadIdx.x;
    const int lane = t & 63, w = t >> 6;
    const int bm = blockIdx.x * 64;
    const int fr = lane & 15;
    const int fq = lane >> 4;
    const int fg = fq * 8;
    const int arow = t >> 2;           // 0..63
    const int acol = (t & 3) * 8;
    const int brow = t >> 2;
    const int bcol = (t & 3) * 8;

    f32x4 acc[12], acc2[12];
    #pragma unroll
    for (int c = 0; c < 12; ++c) {
        acc[c] = (f32x4){0.f, 0.f, 0.f, 0.f};
        acc2[c] = (f32x4){0.f, 0.f, 0.f, 0.f};
    }

    const int ga = bm + arow;
    for (int k0 = 0; k0 < K; k0 += 32) {
        uint4 u0 = make_uint4(0,0,0,0);
        if (ga < M)
            u0 = *reinterpret_cast<const uint4*>(A + (size_t)ga * K + k0 + acol);
        *reinterpret_cast<uint4*>(As + arow * LDA + acol) = u0;
        #pragma unroll
        for (int j = 0; j < 3; ++j) {
            uint4 bv = *reinterpret_cast<const uint4*>(BT + (size_t)(j * 64 + brow) * K + k0 + bcol);
            *reinterpret_cast<uint4*>(Bs + (j * 64 + brow) * LDA + bcol) = bv;
            uint4 b2 = *reinterpret_cast<const uint4*>(BT2 + (size_t)(j * 64 + brow) * K + k0 + bcol);
            *reinterpret_cast<uint4*>(Bs2 + (j * 64 + brow) * LDA + bcol) = b2;
        }
        __syncthreads();
        short8 afr = *reinterpret_cast<const short8*>(As + (w * 16 + fr) * LDA + fg);
        #pragma unroll
        for (int c = 0; c < 12; ++c) {
            short8 bfr = *reinterpret_cast<const short8*>(Bs + (c * 16 + fr) * LDA + fg);
            acc[c] = __builtin_amdgcn_mfma_f32_16x16x32_bf16(afr, bfr, acc[c], 0, 0, 0);
            short8 b2 = *reinterpret_cast<const short8*>(Bs2 + (c * 16 + fr) * LDA + fg);
            acc2[c] = __builtin_amdgcn_mfma_f32_16x16x32_bf16(afr, b2, acc2[c], 0, 0, 0);
        }
        __syncthreads();
    }
    #pragma unroll
    for (int j = 0; j < 4; ++j) {
        int row = bm + w * 16 + fq * 4 + j;
        if (row < M) {
            #pragma unroll
            for (int c = 0; c < 12; ++c) {
                Cb[(size_t)row * FEAT + c * 16 + fr] = (ushort)f2b(acc[c][j]);
                resb[(size_t)row * FEAT + c * 16 + fr] = (ushort)f2b(acc2[c][j]);
            }
        }
    }
    float alv[12], arv[12];
    #pragma unroll
    for (int c = 0; c < 12; ++c) {
        alv[c] = al[c * 16 + fr];
        arv[c] = ar[c * 16 + fr];
    }
    #pragma unroll
    for (int j = 0; j < 4; ++j) {
        int row = bm + w * 16 + fq * 4 + j;
        float pl0 = 0.f, pl1 = 0.f, pl2 = 0.f;
        float pr0 = 0.f, pr1 = 0.f, pr2 = 0.f;
        #pragma unroll
        for (int c = 0; c < 4; ++c)  { pl0 += acc[c][j]*alv[c];  pr0 += acc[c][j]*arv[c]; }
        #pragma unroll
        for (int c = 4; c < 8; ++c)  { pl1 += acc[c][j]*alv[c];  pr1 += acc[c][j]*arv[c]; }
        #pragma unroll
        for (int c = 8; c < 12; ++c) { pl2 += acc[c][j]*alv[c];  pr2 += acc[c][j]*arv[c]; }
        #pragma unroll
        for (int o = 1; o < 16; o <<= 1) {
            pl0 += __shfl_xor(pl0, o); pl1 += __shfl_xor(pl1, o); pl2 += __shfl_xor(pl2, o);
            pr0 += __shfl_xor(pr0, o); pr1 += __shfl_xor(pr1, o); pr2 += __shfl_xor(pr2, o);
        }
        if (fr == 0 && row < M) {
            el4[row] = make_float4(pl0, pl1, pl2, 0.f);
            er4[row] = make_float4(pr0, pr1, pr2, 0.f);
        }
    }
}

// ---------------- CSR build --------------------------------------------------
__global__ void k_hist(const int* __restrict__ dst, int* __restrict__ deg) {
    int e = blockIdx.x * blockDim.x + threadIdx.x;
    if (e < EEN) atomicAdd(&deg[dst[e]], 1);
}

__global__ __launch_bounds__(1024) void k_scan1(const int* __restrict__ deg,
        int* __restrict__ off, int* __restrict__ bsum)
{
    __shared__ int wsums[16];
    __shared__ int wexc[16];
    const int tid = threadIdx.x;
    const int lane = tid & 63, wid = tid >> 6;
    int i = blockIdx.x * 1024 + tid;
    int v = (i < NN) ? deg[i] : 0;
    int incl = v;
    #pragma unroll
    for (int o = 1; o < 64; o <<= 1) {
        int u = __shfl_up(incl, o);
        if (lane >= o) incl += u;
    }
    if (lane == 63) wsums[wid] = incl;
    __syncthreads();
    if (wid == 0) {
        int s = (lane < 16) ? wsums[lane] : 0;
        int si = s;
        #pragma unroll
        for (int o = 1; o < 16; o <<= 1) {
            int u = __shfl_up(si, o);
            if (lane >= o) si += u;
        }
        if (lane < 16) wexc[lane] = si - s;
        if (lane == 15) bsum[blockIdx.x] = si;
    }
    __syncthreads();
    if (i < NN) off[i] = wexc[wid] + incl - v;
}

__global__ __launch_bounds__(64) void k_scan2(const int* __restrict__ bsum,
        int* __restrict__ bexc, int* __restrict__ off)
{
    int lane = threadIdx.x;
    int v = (lane < NB) ? bsum[lane] : 0;
    int incl = v;
    #pragma unroll
    for (int o = 1; o < 64; o <<= 1) {
        int u = __shfl_up(incl, o);
        if (lane >= o) incl += u;
    }
    if (lane < NB) bexc[lane] = incl - v;
    if (lane == 63) off[NN] = incl;
}

__global__ __launch_bounds__(1024) void k_scan3(int* __restrict__ off,
        int* __restrict__ cur, const int* __restrict__ bexc)
{
    int i = blockIdx.x * 1024 + threadIdx.x;
    if (i < NN) {
        int o = off[i] + bexc[blockIdx.x];
        off[i] = o;
        cur[i] = o;
    }
}

__global__ void k_scatter(const int* __restrict__ src, const int* __restrict__ dst,
        const int* __restrict__ et, int* __restrict__ cur, int* __restrict__ srcP)
{
    int e = blockIdx.x * blockDim.x + threadIdx.x;
    if (e < EEN) {
        int p = atomicAdd(&cur[dst[e]], 1);
        srcP[p] = (src[e] << 4) | (et[e] << 28);
    }
}

// ---------------- per-edge-type attention bias tables (both layers) ----------
__global__ __launch_bounds__(192) void k_eetab2(const float* __restrict__ Eemb1,
        const float* __restrict__ We1, const float* __restrict__ ae1,
        float* __restrict__ ee1, const float* __restrict__ Eemb2,
        const float* __restrict__ We2, const float* __restrict__ ae2,
        float* __restrict__ ee2)
{
    const float* Eemb = blockIdx.x ? Eemb2 : Eemb1;
    const float* We   = blockIdx.x ? We2   : We1;
    const float* ae   = blockIdx.x ? ae2   : ae1;
    float* eetab      = blockIdx.x ? ee2   : ee1;
    __shared__ float t1[3 * 64];
    const int t = threadIdx.x;
    const int g = t & 63, h = t >> 6;
    const float* wrow = We + g * FEAT + h * EFD;
    const float* av   = ae + h * EFD;
    float s = 0.f;
    #pragma unroll 8
    for (int f = 0; f < EFD; ++f) s += wrow[f] * av[f];
    t1[h * 64 + g] = s;
    __syncthreads();
    if (t < 24) {
        int tt = t / 3, hh = t - tt * 3;
        float acc = 0.f;
        const float* em = Eemb + tt * EFD;
        const float* tv = t1 + hh * 64;
        #pragma unroll 8
        for (int g2 = 0; g2 < 64; ++g2) acc += em[g2] * tv[g2];
        eetab[tt * 3 + hh] = acc;
    }
}

// ---------------- fused edge-softmax + aggregation (wave per node) -----------
#define GATHER1(J) { \
    float2 gv = *reinterpret_cast<const float2*>(swh + (J)*6); \
    uint2 uu = *reinterpret_cast<const uint2*>(fb + __float_as_int(gv.y)); \
    acc0 += gv.x*blo(uu.x); acc1 += gv.x*bhi(uu.x); \
    acc2 += gv.x*blo(uu.y); acc3 += gv.x*bhi(uu.y); }

template<bool RES, bool FINAL>
__global__ __launch_bounds__(256) void k_attn_agg(const int* __restrict__ off,
        const int* __restrict__ srcP, const float4* __restrict__ el4,
        const float4* __restrict__ er4, const float* __restrict__ eetab,
        const ushort* __restrict__ featb, const ushort* __restrict__ resb,
        void* __restrict__ outv)
{
    __shared__ float shw[4][64 * 6];
    __shared__ float eet[24];
    const int wid = threadIdx.x >> 6, lane = threadIdx.x & 63;
    if (threadIdx.x < 24) eet[threadIdx.x] = eetab[threadIdx.x];
    __syncthreads();
    const int n = blockIdx.x * 4 + wid;
    if (n >= NN) return;
    const int hd = lane >> 4;                  // 0..2 gather head; 3 = idle
    const char* elc = (const char*)el4;
    const char* fb  = (const char*)featb + lane * 8;
    float* sw = shw[wid];

    const int beg = off[n], end = off[n + 1];
    const float4 erv = er4[n];
    float acc0 = 0.f, acc1 = 0.f, acc2 = 0.f, acc3 = 0.f;
    float dl0 = 0.f, dl1 = 0.f, dl2 = 0.f;

    for (int c0 = beg; c0 < end; c0 += 64) {
        const int e = c0 + lane;
        float p0 = 0.f, p1 = 0.f, p2 = 0.f;
        int boff = 0;
        if (e < end) {
            int sp = srcP[e];
            int s16 = sp & SMASK;
            int tt = ((unsigned)sp) >> 28;
            float4 ev = *reinterpret_cast<const float4*>(elc + s16);
            float l0 = ev.x + erv.x + eet[tt*3+0];
            float l1 = ev.y + erv.y + eet[tt*3+1];
            float l2 = ev.z + erv.z + eet[tt*3+2];
            l0 = l0 > 0.f ? l0 : NEG_ * l0;
            l1 = l1 > 0.f ? l1 : NEG_ * l1;
            l2 = l2 > 0.f ? l2 : NEG_ * l2;
            p0 = __expf(l0); p1 = __expf(l1); p2 = __expf(l2);
            boff = s16 * 24;                   // s*384 bytes into featb
        }
        dl0 += p0; dl1 += p1; dl2 += p2;
        const float bf = __int_as_float(boff);
        float* sl = sw + lane * 6;
        *reinterpret_cast<float2*>(sl + 0) = make_float2(p0, bf);
        *reinterpret_cast<float2*>(sl + 2) = make_float2(p1, bf);
        *reinterpret_cast<float2*>(sl + 4) = make_float2(p2, bf);
        const int cnt = min(64, end - c0);
        const float* swh = sw + hd * 2;
        if (lane < 48) {
            int j = 0;
            for (; j + 8 <= cnt; j += 8) {
                float2 g0 = *reinterpret_cast<const float2*>(swh + (j+0)*6);
                float2 g1 = *reinterpret_cast<const float2*>(swh + (j+1)*6);
                float2 g2 = *reinterpret_cast<const float2*>(swh + (j+2)*6);
                float2 g3 = *reinterpret_cast<const float2*>(swh + (j+3)*6);
                float2 g4 = *reinterpret_cast<const float2*>(swh + (j+4)*6);
                float2 g5 = *reinterpret_cast<const float2*>(swh + (j+5)*6);
                float2 g6 = *reinterpret_cast<const float2*>(swh + (j+6)*6);
                float2 g7 = *reinterpret_cast<const float2*>(swh + (j+7)*6);
                uint2 u0 = *reinterpret_cast<const uint2*>(fb + __float_as_int(g0.y));
                uint2 u1 = *reinterpret_cast<const uint2*>(fb + __float_as_int(g1.y));
                uint2 u2 = *reinterpret_cast<const uint2*>(fb + __float_as_int(g2.y));
                uint2 u3 = *reinterpret_cast<const uint2*>(fb + __float_as_int(g3.y));
                uint2 u4 = *reinterpret_cast<const uint2*>(fb + __float_as_int(g4.y));
                uint2 u5 = *reinterpret_cast<const uint2*>(fb + __float_as_int(g5.y));
                uint2 u6 = *reinterpret_cast<const uint2*>(fb + __float_as_int(g6.y));
                uint2 u7 = *reinterpret_cast<const uint2*>(fb + __float_as_int(g7.y));
                acc0 += g0.x*blo(u0.x) + g1.x*blo(u1.x) + g2.x*blo(u2.x) + g3.x*blo(u3.x);
                acc1 += g0.x*bhi(u0.x) + g1.x*bhi(u1.x) + g2.x*bhi(u2.x) + g3.x*bhi(u3.x);
                acc2 += g0.x*blo(u0.y) + g1.x*blo(u1.y) + g2.x*blo(u2.y) + g3.x*blo(u3.y);
                acc3 += g0.x*bhi(u0.y) + g1.x*bhi(u1.y) + g2.x*bhi(u2.y) + g3.x*bhi(u3.y);
                acc0 += g4.x*blo(u4.x) + g5.x*blo(u5.x) + g6.x*blo(u6.x) + g7.x*blo(u7.x);
                acc1 += g4.x*bhi(u4.x) + g5.x*bhi(u5.x) + g6.x*bhi(u6.x) + g7.x*bhi(u7.x);
                acc2 += g4.x*blo(u4.y) + g5.x*blo(u5.y) + g6.x*blo(u6.y) + g7.x*blo(u7.y);
                acc3 += g4.x*bhi(u4.y) + g5.x*bhi(u5.y) + g6.x*bhi(u6.y) + g7.x*bhi(u7.y);
            }
            if (j + 4 <= cnt) {
                float2 g0 = *reinterpret_cast<const float2*>(swh + (j+0)*6);
                float2 g1 = *reinterpret_cast<const float2*>(swh + (j+1)*6);
                float2 g2 = *reinterpret_cast<const float2*>(swh + (j+2)*6);
                float2 g3 = *reinterpret_cast<const float2*>(swh + (j+3)*6);
                uint2 u0 = *reinterpret_cast<const uint2*>(fb + __float_as_int(g0.y));
                uint2 u1 = *reinterpret_cast<const uint2*>(fb + __float_as_int(g1.y));
                uint2 u2 = *reinterpret_cast<const uint2*>(fb + __float_as_int(g2.y));
                uint2 u3 = *reinterpret_cast<const uint2*>(fb + __float_as_int(g3.y));
                acc0 += g0.x*blo(u0.x) + g1.x*blo(u1.x) + g2.x*blo(u2.x) + g3.x*blo(u3.x);
                acc1 += g0.x*bhi(u0.x) + g1.x*bhi(u1.x) + g2.x*bhi(u2.x) + g3.x*bhi(u3.x);
                acc2 += g0.x*blo(u0.y) + g1.x*blo(u1.y) + g2.x*blo(u2.y) + g3.x*blo(u3.y);
                acc3 += g0.x*bhi(u0.y) + g1.x*bhi(u1.y) + g2.x*bhi(u2.y) + g3.x*bhi(u3.y);
                j += 4;
            }
            for (; j < cnt; ++j) GATHER1(j)
        }
    }
    #pragma unroll
    for (int o = 32; o > 0; o >>= 1) {
        dl0 += __shfl_xor(dl0, o);
        dl1 += __shfl_xor(dl1, o);
        dl2 += __shfl_xor(dl2, o);
    }
    const float den = hd == 0 ? dl0 : (hd == 1 ? dl1 : dl2);
    const float inv = 1.f / fmaxf(den, EPSF);
    acc0 *= inv; acc1 *= inv; acc2 *= inv; acc3 *= inv;
    if (RES) {
        if (lane < 48) {
            uint2 r = *reinterpret_cast<const uint2*>((const char*)resb + (size_t)n * 384 + lane * 8);
            acc0 += blo(r.x); acc1 += bhi(r.x);
            acc2 += blo(r.y); acc3 += bhi(r.y);
        }
    }
    acc0 = acc0 > 0.f ? acc0 : expm1f(acc0);
    acc1 = acc1 > 0.f ? acc1 : expm1f(acc1);
    acc2 = acc2 > 0.f ? acc2 : expm1f(acc2);
    acc3 = acc3 > 0.f ? acc3 : expm1f(acc3);
    if (!FINAL) {
        if (lane < 48) {
            ushort4 o4;
            o4.x = (ushort)f2b(acc0); o4.y = (ushort)f2b(acc1);
            o4.z = (ushort)f2b(acc2); o4.w = (ushort)f2b(acc3);
            ((ushort4*)outv)[(size_t)n * 48 + lane] = o4;
        }
    } else {
        float b0 = __shfl(acc0, lane + 16), c0v = __shfl(acc0, lane + 32);
        float b1 = __shfl(acc1, lane + 16), c1v = __shfl(acc1, lane + 32);
        float b2 = __shfl(acc2, lane + 16), c2v = __shfl(acc2, lane + 32);
        float b3 = __shfl(acc3, lane + 16), c3v = __shfl(acc3, lane + 32);
        float mm0 = (acc0 + b0 + c0v) * (1.f / 3.f);
        float mm1 = (acc1 + b1 + c1v) * (1.f / 3.f);
        float mm2 = (acc2 + b2 + c2v) * (1.f / 3.f);
        float mm3 = (acc3 + b3 + c3v) * (1.f / 3.f);
        float ss = (lane < 16) ? (mm0*mm0 + mm1*mm1 + mm2*mm2 + mm3*mm3) : 0.f;
        #pragma unroll
        for (int o = 1; o < 16; o <<= 1) ss += __shfl_xor(ss, o);
        float nrm = sqrtf(ss);
        float invn = 1.f / fmaxf(nrm, EPSF);
        if (lane < 16) {
            ((float4*)outv)[(size_t)n * 16 + lane] =
                make_float4(mm0 * invn, mm1 * invn, mm2 * invn, mm3 * invn);
        }
    }
}

extern "C" void kernel_launch(void* const* d_in, const int* in_sizes, int n_in,
                              void* d_out, int out_size, void* d_ws, size_t ws_size,
                              hipStream_t stream)
{
    const float* x     = (const float*)d_in[0];
    const int*   src   = (const int*)d_in[1];
    const int*   dst   = (const int*)d_in[2];
    const int*   efeat = (const int*)d_in[3];
    const float* W1    = (const float*)d_in[4];
    const float* Eemb1 = (const float*)d_in[5];
    const float* We1   = (const float*)d_in[6];
    const float* al1   = (const float*)d_in[7];
    const float* ar1   = (const float*)d_in[8];
    const float* ae1   = (const float*)d_in[9];
    const float* W2    = (const float*)d_in[10];
    const float* Eemb2 = (const float*)d_in[11];
    const float* We2   = (const float*)d_in[12];
    const float* al2   = (const float*)d_in[13];
    const float* ar2   = (const float*)d_in[14];
    const float* ae2   = (const float*)d_in[15];
    const float* Wres2 = (const float*)d_in[16];

    char* w = (char*)d_ws;
    auto alloc = [&](size_t bytes) {
        char* p = w;
        w += (bytes + 255) & ~(size_t)255;
        return p;
    };
    ushort* featb = (ushort*)alloc((size_t)NN * FEAT * 2);   // gemm out (bf16)
    ushort* h1b   = (ushort*)alloc((size_t)NN * FEAT * 2);   // layer1 out (bf16)
    ushort* resb  = (ushort*)alloc((size_t)NN * FEAT * 2);   // residual (bf16)
    float4* el4   = (float4*)alloc((size_t)NN * 16);
    float4* er4   = (float4*)alloc((size_t)NN * 16);
    int*    deg   = (int*)alloc((size_t)NN * 4);
    int*    off   = (int*)alloc((size_t)(NN + 1) * 4);
    int*    cur   = (int*)alloc((size_t)NN * 4);
    int*    srcP  = (int*)alloc((size_t)EEN * 4);
    int*    bsum  = (int*)alloc(64 * 4);
    int*    bexc  = (int*)alloc(64 * 4);
    ushort* w1bt  = (ushort*)alloc((size_t)FEAT * INF_ * 2);
    ushort* w2bt  = (ushort*)alloc((size_t)FEAT * FEAT * 2);
    ushort* wrbt  = (ushort*)alloc((size_t)FEAT * FEAT * 2);
    float*  ee1   = (float*)alloc(24 * 4);
    float*  ee2   = (float*)alloc(24 * 4);

    hipMemsetAsync(deg, 0, (size_t)NN * 4, stream);

    const int eb = (EEN + 255) / 256;
    k_hist<<<eb, 256, 0, stream>>>(dst, deg);
    k_scan1<<<NB, 1024, 0, stream>>>(deg, off, bsum);
    k_scan2<<<1, 64, 0, stream>>>(bsum, bexc, off);
    k_scan3<<<NB, 1024, 0, stream>>>(off, cur, bexc);
    k_scatter<<<eb, 256, 0, stream>>>(src, dst, efeat, cur, srcP);
    k_eetab2<<<2, 192, 0, stream>>>(Eemb1, We1, ae1, ee1, Eemb2, We2, ae2, ee2);
    k_wtrans3<<<120, 256, 0, stream>>>(W1, w1bt, W2, w2bt, Wres2, wrbt);

    const int nb4 = (NN + 3) / 4;
    // ---- layer 1 ----
    gemm_mfma1<<<(NN + 127) / 128, 256, 0, stream>>>(x, w1bt, featb,
            el4, er4, al1, ar1, NN, INF_);
    k_attn_agg<false, false><<<nb4, 256, 0, stream>>>(off, srcP, el4, er4, ee1,
            featb, nullptr, h1b);
    // ---- layer 2 (W2 and Wres in one pass) ----
    gemm_mfma2<<<(NN + 63) / 64, 256, 0, stream>>>(h1b, w2bt, wrbt, featb,
            resb, el4, er4, al2, ar2, NN, FEAT);
    k_attn_agg<true, true><<<nb4, 256, 0, stream>>>(off, srcP, el4, er4, ee2,
            featb, resb, (float*)d_out);
}

// Round 9
// 267.857 us; speedup vs baseline: 1.0578x; 1.0578x over previous
//
#include <hip/hip_runtime.h>
#include <cstdint>
#include <cstddef>

#define NN   50000
#define EEN  800000
#define INF_ 256
#define HH   3
#define FEAT 192   // H*D
#define EFD  64
#define NEG_ 0.2f
#define EPSF 1e-12f
#define SMASK 0x0FFFFFF0   // s*16 field in srcP
#define NB   ((NN + 1023) / 1024)

typedef __attribute__((ext_vector_type(8))) short short8;
typedef __attribute__((ext_vector_type(4))) float f32x4;

static __device__ __forceinline__ float4 ld4(const float* p) {
    return *reinterpret_cast<const float4*>(p);
}
static __device__ __forceinline__ uint f2b(float f) {
    union { float f; uint32_t u; } v; v.f = f;
    uint32_t u = v.u;
    return (u + 0x7FFFu + ((u >> 16) & 1u)) >> 16;
}
static __device__ __forceinline__ uint pack2(float a, float b) {
    return f2b(a) | (f2b(b) << 16);
}
static __device__ __forceinline__ float blo(uint u) {
    return __uint_as_float(u << 16);
}
static __device__ __forceinline__ float bhi(uint u) {
    return __uint_as_float(u & 0xFFFF0000u);
}

// ---------------- LDS-tiled weight transpose+convert -------------------------
// W[K][N] f32 -> BT[N][K] bf16, all dims multiples of 32
static __device__ __forceinline__ void trans_tile(const float* __restrict__ W,
        ushort* __restrict__ BT, int K, int N, int kt, int nt)
{
    __shared__ float tile[32][33];
    const int tx = threadIdx.x & 31, ty = threadIdx.x >> 5;  // 32 x 8
    #pragma unroll
    for (int r = 0; r < 4; ++r) {
        int row = kt * 32 + ty + r * 8;
        int col = nt * 32 + tx;
        tile[ty + r * 8][tx] = W[(size_t)row * N + col];
    }
    __syncthreads();
    #pragma unroll
    for (int r = 0; r < 4; ++r) {
        int n = nt * 32 + ty + r * 8;
        int k = kt * 32 + tx;
        BT[(size_t)n * K + k] = (ushort)f2b(tile[tx][ty + r * 8]);
    }
}

__global__ __launch_bounds__(256) void k_wtrans3(const float* __restrict__ W1,
        ushort* __restrict__ o1, const float* __restrict__ W2,
        ushort* __restrict__ o2, const float* __restrict__ W3,
        ushort* __restrict__ o3)
{
    int b = blockIdx.x;
    if (b < 48) {            // W1: K=256 (8 ktiles) x N=192 (6 ntiles)
        trans_tile(W1, o1, INF_, FEAT, b & 7, b >> 3);
    } else if (b < 84) {     // W2: 6 x 6
        int i = b - 48;
        trans_tile(W2, o2, FEAT, FEAT, i % 6, i / 6);
    } else {                 // W3: 6 x 6
        int i = b - 84;
        trans_tile(W3, o3, FEAT, FEAT, i % 6, i / 6);
    }
}

// ---------------- GEMM1: 128-row tile, full-N(192), fused el/er --------------
#define LDA 40   // padded LDS row stride (ushort)
__global__ __launch_bounds__(256) void gemm_mfma1(const float* __restrict__ A,
        const ushort* __restrict__ BT, ushort* __restrict__ Cb,
        float4* __restrict__ el4, float4* __restrict__ er4,
        const float* __restrict__ al, const float* __restrict__ ar,
        int M, int K)
{
    __shared__ ushort As[128 * LDA];
    __shared__ ushort Bs[192 * LDA];
    const int t = threadIdx.x;
    const int lane = t & 63, w = t >> 6;
    const int bm = blockIdx.x * 128;
    const int fr = lane & 15;
    const int fq = lane >> 4;
    const int fg = fq * 8;
    const int arow = t >> 1;           // 0..127
    const int acol = (t & 1) * 8;      // 0 or 8 (plus +16 later)
    const int brow = t >> 2;           // 0..63
    const int bcol = (t & 3) * 8;

    f32x4 acc[2][12];
    #pragma unroll
    for (int i = 0; i < 2; ++i)
        #pragma unroll
        for (int c = 0; c < 12; ++c)
            acc[i][c] = (f32x4){0.f, 0.f, 0.f, 0.f};

    const int ga = bm + arow;
    for (int k0 = 0; k0 < K; k0 += 32) {
        uint4 u0 = make_uint4(0,0,0,0), u1 = u0;
        if (ga < M) {
            const float* ap = A + (size_t)ga * K + k0 + acol;
            float4 f0 = ld4(ap), f1 = ld4(ap + 4);
            float4 f2v = ld4(ap + 16), f3 = ld4(ap + 20);
            u0 = make_uint4(pack2(f0.x,f0.y), pack2(f0.z,f0.w),
                            pack2(f1.x,f1.y), pack2(f1.z,f1.w));
            u1 = make_uint4(pack2(f2v.x,f2v.y), pack2(f2v.z,f2v.w),
                            pack2(f3.x,f3.y), pack2(f3.z,f3.w));
        }
        *reinterpret_cast<uint4*>(As + arow * LDA + acol) = u0;
        *reinterpret_cast<uint4*>(As + arow * LDA + acol + 16) = u1;
        #pragma unroll
        for (int j = 0; j < 3; ++j) {
            uint4 bv = *reinterpret_cast<const uint4*>(BT + (size_t)(j * 64 + brow) * K + k0 + bcol);
            *reinterpret_cast<uint4*>(Bs + (j * 64 + brow) * LDA + bcol) = bv;
        }
        __syncthreads();
        short8 afr0 = *reinterpret_cast<const short8*>(As + (w * 32 + fr) * LDA + fg);
        short8 afr1 = *reinterpret_cast<const short8*>(As + (w * 32 + 16 + fr) * LDA + fg);
        #pragma unroll
        for (int c = 0; c < 12; ++c) {
            short8 bfr = *reinterpret_cast<const short8*>(Bs + (c * 16 + fr) * LDA + fg);
            acc[0][c] = __builtin_amdgcn_mfma_f32_16x16x32_bf16(afr0, bfr, acc[0][c], 0, 0, 0);
            acc[1][c] = __builtin_amdgcn_mfma_f32_16x16x32_bf16(afr1, bfr, acc[1][c], 0, 0, 0);
        }
        __syncthreads();
    }
    #pragma unroll
    for (int i = 0; i < 2; ++i) {
        #pragma unroll
        for (int j = 0; j < 4; ++j) {
            int row = bm + w * 32 + i * 16 + fq * 4 + j;
            if (row < M) {
                #pragma unroll
                for (int c = 0; c < 12; ++c)
                    Cb[(size_t)row * FEAT + c * 16 + fr] = (ushort)f2b(acc[i][c][j]);
            }
        }
    }
    float alv[12], arv[12];
    #pragma unroll
    for (int c = 0; c < 12; ++c) {
        alv[c] = al[c * 16 + fr];
        arv[c] = ar[c * 16 + fr];
    }
    #pragma unroll
    for (int i = 0; i < 2; ++i) {
        #pragma unroll
        for (int j = 0; j < 4; ++j) {
            int row = bm + w * 32 + i * 16 + fq * 4 + j;
            float pl0 = 0.f, pl1 = 0.f, pl2 = 0.f;
            float pr0 = 0.f, pr1 = 0.f, pr2 = 0.f;
            #pragma unroll
            for (int c = 0; c < 4; ++c)  { pl0 += acc[i][c][j]*alv[c];  pr0 += acc[i][c][j]*arv[c]; }
            #pragma unroll
            for (int c = 4; c < 8; ++c)  { pl1 += acc[i][c][j]*alv[c];  pr1 += acc[i][c][j]*arv[c]; }
            #pragma unroll
            for (int c = 8; c < 12; ++c) { pl2 += acc[i][c][j]*alv[c];  pr2 += acc[i][c][j]*arv[c]; }
            #pragma unroll
            for (int o = 1; o < 16; o <<= 1) {
                pl0 += __shfl_xor(pl0, o); pl1 += __shfl_xor(pl1, o); pl2 += __shfl_xor(pl2, o);
                pr0 += __shfl_xor(pr0, o); pr1 += __shfl_xor(pr1, o); pr2 += __shfl_xor(pr2, o);
            }
            if (fr == 0 && row < M) {
                el4[row] = make_float4(pl0, pl1, pl2, 0.f);
                er4[row] = make_float4(pr0, pr1, pr2, 0.f);
            }
        }
    }
}

// ---------------- GEMM2: 64-row tile, dual-B, fused el/er --------------------
__global__ __launch_bounds__(256) void gemm_mfma2(const ushort* __restrict__ A,
        const ushort* __restrict__ BT, const ushort* __restrict__ BT2,
        ushort* __restrict__ Cb, ushort* __restrict__ resb,
        float4* __restrict__ el4, float4* __restrict__ er4,
        const float* __restrict__ al, const float* __restrict__ ar,
        int M, int K)
{
    __shared__ ushort As[64 * LDA];
    __shared__ ushort Bs[192 * LDA];
    __shared__ ushort Bs2[192 * LDA];
    const int t = threadIdx.x;
    const int lane = t & 63, w = t >> 6;
    const int bm = blockIdx.x * 64;
    const int fr = lane & 15;
    const int fq = lane >> 4;
    const int fg = fq * 8;
    const int arow = t >> 2;           // 0..63
    const int acol = (t & 3) * 8;
    const int brow = t >> 2;
    const int bcol = (t & 3) * 8;

    f32x4 acc[12], acc2[12];
    #pragma unroll
    for (int c = 0; c < 12; ++c) {
        acc[c] = (f32x4){0.f, 0.f, 0.f, 0.f};
        acc2[c] = (f32x4){0.f, 0.f, 0.f, 0.f};
    }

    const int ga = bm + arow;
    for (int k0 = 0; k0 < K; k0 += 32) {
        uint4 u0 = make_uint4(0,0,0,0);
        if (ga < M)
            u0 = *reinterpret_cast<const uint4*>(A + (size_t)ga * K + k0 + acol);
        *reinterpret_cast<uint4*>(As + arow * LDA + acol) = u0;
        #pragma unroll
        for (int j = 0; j < 3; ++j) {
            uint4 bv = *reinterpret_cast<const uint4*>(BT + (size_t)(j * 64 + brow) * K + k0 + bcol);
            *reinterpret_cast<uint4*>(Bs + (j * 64 + brow) * LDA + bcol) = bv;
            uint4 b2 = *reinterpret_cast<const uint4*>(BT2 + (size_t)(j * 64 + brow) * K + k0 + bcol);
            *reinterpret_cast<uint4*>(Bs2 + (j * 64 + brow) * LDA + bcol) = b2;
        }
        __syncthreads();
        short8 afr = *reinterpret_cast<const short8*>(As + (w * 16 + fr) * LDA + fg);
        #pragma unroll
        for (int c = 0; c < 12; ++c) {
            short8 bfr = *reinterpret_cast<const short8*>(Bs + (c * 16 + fr) * LDA + fg);
            acc[c] = __builtin_amdgcn_mfma_f32_16x16x32_bf16(afr, bfr, acc[c], 0, 0, 0);
            short8 b2 = *reinterpret_cast<const short8*>(Bs2 + (c * 16 + fr) * LDA + fg);
            acc2[c] = __builtin_amdgcn_mfma_f32_16x16x32_bf16(afr, b2, acc2[c], 0, 0, 0);
        }
        __syncthreads();
    }
    #pragma unroll
    for (int j = 0; j < 4; ++j) {
        int row = bm + w * 16 + fq * 4 + j;
        if (row < M) {
            #pragma unroll
            for (int c = 0; c < 12; ++c) {
                Cb[(size_t)row * FEAT + c * 16 + fr] = (ushort)f2b(acc[c][j]);
                resb[(size_t)row * FEAT + c * 16 + fr] = (ushort)f2b(acc2[c][j]);
            }
        }
    }
    float alv[12], arv[12];
    #pragma unroll
    for (int c = 0; c < 12; ++c) {
        alv[c] = al[c * 16 + fr];
        arv[c] = ar[c * 16 + fr];
    }
    #pragma unroll
    for (int j = 0; j < 4; ++j) {
        int row = bm + w * 16 + fq * 4 + j;
        float pl0 = 0.f, pl1 = 0.f, pl2 = 0.f;
        float pr0 = 0.f, pr1 = 0.f, pr2 = 0.f;
        #pragma unroll
        for (int c = 0; c < 4; ++c)  { pl0 += acc[c][j]*alv[c];  pr0 += acc[c][j]*arv[c]; }
        #pragma unroll
        for (int c = 4; c < 8; ++c)  { pl1 += acc[c][j]*alv[c];  pr1 += acc[c][j]*arv[c]; }
        #pragma unroll
        for (int c = 8; c < 12; ++c) { pl2 += acc[c][j]*alv[c];  pr2 += acc[c][j]*arv[c]; }
        #pragma unroll
        for (int o = 1; o < 16; o <<= 1) {
            pl0 += __shfl_xor(pl0, o); pl1 += __shfl_xor(pl1, o); pl2 += __shfl_xor(pl2, o);
            pr0 += __shfl_xor(pr0, o); pr1 += __shfl_xor(pr1, o); pr2 += __shfl_xor(pr2, o);
        }
        if (fr == 0 && row < M) {
            el4[row] = make_float4(pl0, pl1, pl2, 0.f);
            er4[row] = make_float4(pr0, pr1, pr2, 0.f);
        }
    }
}

// ---------------- CSR build --------------------------------------------------
__global__ void k_hist(const int* __restrict__ dst, int* __restrict__ deg) {
    int e = blockIdx.x * blockDim.x + threadIdx.x;
    if (e < EEN) atomicAdd(&deg[dst[e]], 1);
}

__global__ __launch_bounds__(1024) void k_scan1(const int* __restrict__ deg,
        int* __restrict__ off, int* __restrict__ bsum)
{
    __shared__ int wsums[16];
    __shared__ int wexc[16];
    const int tid = threadIdx.x;
    const int lane = tid & 63, wid = tid >> 6;
    int i = blockIdx.x * 1024 + tid;
    int v = (i < NN) ? deg[i] : 0;
    int incl = v;
    #pragma unroll
    for (int o = 1; o < 64; o <<= 1) {
        int u = __shfl_up(incl, o);
        if (lane >= o) incl += u;
    }
    if (lane == 63) wsums[wid] = incl;
    __syncthreads();
    if (wid == 0) {
        int s = (lane < 16) ? wsums[lane] : 0;
        int si = s;
        #pragma unroll
        for (int o = 1; o < 16; o <<= 1) {
            int u = __shfl_up(si, o);
            if (lane >= o) si += u;
        }
        if (lane < 16) wexc[lane] = si - s;
        if (lane == 15) bsum[blockIdx.x] = si;
    }
    __syncthreads();
    if (i < NN) off[i] = wexc[wid] + incl - v;
}

__global__ __launch_bounds__(64) void k_scan2(const int* __restrict__ bsum,
        int* __restrict__ bexc, int* __restrict__ off)
{
    int lane = threadIdx.x;
    int v = (lane < NB) ? bsum[lane] : 0;
    int incl = v;
    #pragma unroll
    for (int o = 1; o < 64; o <<= 1) {
        int u = __shfl_up(incl, o);
        if (lane >= o) incl += u;
    }
    if (lane < NB) bexc[lane] = incl - v;
    if (lane == 63) off[NN] = incl;
}

__global__ __launch_bounds__(1024) void k_scan3(int* __restrict__ off,
        int* __restrict__ cur, const int* __restrict__ bexc)
{
    int i = blockIdx.x * 1024 + threadIdx.x;
    if (i < NN) {
        int o = off[i] + bexc[blockIdx.x];
        off[i] = o;
        cur[i] = o;
    }
}

__global__ void k_scatter(const int* __restrict__ src, const int* __restrict__ dst,
        const int* __restrict__ et, int* __restrict__ cur, int* __restrict__ srcP)
{
    int e = blockIdx.x * blockDim.x + threadIdx.x;
    if (e < EEN) {
        int p = atomicAdd(&cur[dst[e]], 1);
        srcP[p] = (src[e] << 4) | (et[e] << 28);
    }
}

// ---------------- per-edge-type attention bias tables (both layers) ----------
__global__ __launch_bounds__(192) void k_eetab2(const float* __restrict__ Eemb1,
        const float* __restrict__ We1, const float* __restrict__ ae1,
        float* __restrict__ ee1, const float* __restrict__ Eemb2,
        const float* __restrict__ We2, const float* __restrict__ ae2,
        float* __restrict__ ee2)
{
    const float* Eemb = blockIdx.x ? Eemb2 : Eemb1;
    const float* We   = blockIdx.x ? We2   : We1;
    const float* ae   = blockIdx.x ? ae2   : ae1;
    float* eetab      = blockIdx.x ? ee2   : ee1;
    __shared__ float t1[3 * 64];
    const int t = threadIdx.x;
    const int g = t & 63, h = t >> 6;
    const float* wrow = We + g * FEAT + h * EFD;
    const float* av   = ae + h * EFD;
    float s = 0.f;
    #pragma unroll 8
    for (int f = 0; f < EFD; ++f) s += wrow[f] * av[f];
    t1[h * 64 + g] = s;
    __syncthreads();
    if (t < 24) {
        int tt = t / 3, hh = t - tt * 3;
        float acc = 0.f;
        const float* em = Eemb + tt * EFD;
        const float* tv = t1 + hh * 64;
        #pragma unroll 8
        for (int g2 = 0; g2 < 64; ++g2) acc += em[g2] * tv[g2];
        eetab[tt * 3 + hh] = acc;
    }
}

// ---------------- fused edge-softmax + aggregation (wave per node) -----------
// (round-7 proven version: 4-deep unroll, in-loop predicate, VGPR 32)
#define GATHER1(J) { \
    float2 gv = *reinterpret_cast<const float2*>(swh + (J)*6); \
    uint2 uu = *reinterpret_cast<const uint2*>(fb + __float_as_int(gv.y)); \
    acc0 += gv.x*blo(uu.x); acc1 += gv.x*bhi(uu.x); \
    acc2 += gv.x*blo(uu.y); acc3 += gv.x*bhi(uu.y); }

template<bool RES, bool FINAL>
__global__ __launch_bounds__(256) void k_attn_agg(const int* __restrict__ off,
        const int* __restrict__ srcP, const float4* __restrict__ el4,
        const float4* __restrict__ er4, const float* __restrict__ eetab,
        const ushort* __restrict__ featb, const ushort* __restrict__ resb,
        void* __restrict__ outv)
{
    __shared__ float shw[4][64 * 6];
    __shared__ float eet[24];
    const int wid = threadIdx.x >> 6, lane = threadIdx.x & 63;
    if (threadIdx.x < 24) eet[threadIdx.x] = eetab[threadIdx.x];
    __syncthreads();
    const int n = blockIdx.x * 4 + wid;
    if (n >= NN) return;
    const int hd = lane >> 4;                  // 0..2 gather head; 3 = idle
    const char* elc = (const char*)el4;
    const char* fb  = (const char*)featb + lane * 8;
    float* sw = shw[wid];

    const int beg = off[n], end = off[n + 1];
    const float4 erv = er4[n];
    float acc0 = 0.f, acc1 = 0.f, acc2 = 0.f, acc3 = 0.f;
    float dl0 = 0.f, dl1 = 0.f, dl2 = 0.f;

    for (int c0 = beg; c0 < end; c0 += 64) {
        const int e = c0 + lane;
        float p0 = 0.f, p1 = 0.f, p2 = 0.f;
        int boff = 0;
        if (e < end) {
            int sp = srcP[e];
            int s16 = sp & SMASK;
            int tt = ((unsigned)sp) >> 28;
            float4 ev = *reinterpret_cast<const float4*>(elc + s16);
            float l0 = ev.x + erv.x + eet[tt*3+0];
            float l1 = ev.y + erv.y + eet[tt*3+1];
            float l2 = ev.z + erv.z + eet[tt*3+2];
            l0 = l0 > 0.f ? l0 : NEG_ * l0;
            l1 = l1 > 0.f ? l1 : NEG_ * l1;
            l2 = l2 > 0.f ? l2 : NEG_ * l2;
            p0 = __expf(l0); p1 = __expf(l1); p2 = __expf(l2);
            boff = s16 * 24;                   // s*384 bytes into featb
        }
        dl0 += p0; dl1 += p1; dl2 += p2;
        const float bf = __int_as_float(boff);
        float* sl = sw + lane * 6;
        *reinterpret_cast<float2*>(sl + 0) = make_float2(p0, bf);
        *reinterpret_cast<float2*>(sl + 2) = make_float2(p1, bf);
        *reinterpret_cast<float2*>(sl + 4) = make_float2(p2, bf);
        const int cnt = min(64, end - c0);
        const float* swh = sw + hd * 2;
        int j = 0;
        for (; j + 4 <= cnt; j += 4) {
            if (lane < 48) {
                float2 g0 = *reinterpret_cast<const float2*>(swh + (j+0)*6);
                float2 g1 = *reinterpret_cast<const float2*>(swh + (j+1)*6);
                float2 g2 = *reinterpret_cast<const float2*>(swh + (j+2)*6);
                float2 g3 = *reinterpret_cast<const float2*>(swh + (j+3)*6);
                uint2 u0 = *reinterpret_cast<const uint2*>(fb + __float_as_int(g0.y));
                uint2 u1 = *reinterpret_cast<const uint2*>(fb + __float_as_int(g1.y));
                uint2 u2 = *reinterpret_cast<const uint2*>(fb + __float_as_int(g2.y));
                uint2 u3 = *reinterpret_cast<const uint2*>(fb + __float_as_int(g3.y));
                acc0 += g0.x*blo(u0.x) + g1.x*blo(u1.x) + g2.x*blo(u2.x) + g3.x*blo(u3.x);
                acc1 += g0.x*bhi(u0.x) + g1.x*bhi(u1.x) + g2.x*bhi(u2.x) + g3.x*bhi(u3.x);
                acc2 += g0.x*blo(u0.y) + g1.x*blo(u1.y) + g2.x*blo(u2.y) + g3.x*blo(u3.y);
                acc3 += g0.x*bhi(u0.y) + g1.x*bhi(u1.y) + g2.x*bhi(u2.y) + g3.x*bhi(u3.y);
            }
        }
        for (; j < cnt; ++j) {
            if (lane < 48) GATHER1(j)
        }
    }
    #pragma unroll
    for (int o = 32; o > 0; o >>= 1) {
        dl0 += __shfl_xor(dl0, o);
        dl1 += __shfl_xor(dl1, o);
        dl2 += __shfl_xor(dl2, o);
    }
    const float den = hd == 0 ? dl0 : (hd == 1 ? dl1 : dl2);
    const float inv = 1.f / fmaxf(den, EPSF);
    acc0 *= inv; acc1 *= inv; acc2 *= inv; acc3 *= inv;
    if (RES) {
        if (lane < 48) {
            uint2 r = *reinterpret_cast<const uint2*>((const char*)resb + (size_t)n * 384 + lane * 8);
            acc0 += blo(r.x); acc1 += bhi(r.x);
            acc2 += blo(r.y); acc3 += bhi(r.y);
        }
    }
    acc0 = acc0 > 0.f ? acc0 : expm1f(acc0);
    acc1 = acc1 > 0.f ? acc1 : expm1f(acc1);
    acc2 = acc2 > 0.f ? acc2 : expm1f(acc2);
    acc3 = acc3 > 0.f ? acc3 : expm1f(acc3);
    if (!FINAL) {
        if (lane < 48) {
            ushort4 o4;
            o4.x = (ushort)f2b(acc0); o4.y = (ushort)f2b(acc1);
            o4.z = (ushort)f2b(acc2); o4.w = (ushort)f2b(acc3);
            ((ushort4*)outv)[(size_t)n * 48 + lane] = o4;
        }
    } else {
        float b0 = __shfl(acc0, lane + 16), c0v = __shfl(acc0, lane + 32);
        float b1 = __shfl(acc1, lane + 16), c1v = __shfl(acc1, lane + 32);
        float b2 = __shfl(acc2, lane + 16), c2v = __shfl(acc2, lane + 32);
        float b3 = __shfl(acc3, lane + 16), c3v = __shfl(acc3, lane + 32);
        float mm0 = (acc0 + b0 + c0v) * (1.f / 3.f);
        float mm1 = (acc1 + b1 + c1v) * (1.f / 3.f);
        float mm2 = (acc2 + b2 + c2v) * (1.f / 3.f);
        float mm3 = (acc3 + b3 + c3v) * (1.f / 3.f);
        float ss = (lane < 16) ? (mm0*mm0 + mm1*mm1 + mm2*mm2 + mm3*mm3) : 0.f;
        #pragma unroll
        for (int o = 1; o < 16; o <<= 1) ss += __shfl_xor(ss, o);
        float nrm = sqrtf(ss);
        float invn = 1.f / fmaxf(nrm, EPSF);
        if (lane < 16) {
            ((float4*)outv)[(size_t)n * 16 + lane] =
                make_float4(mm0 * invn, mm1 * invn, mm2 * invn, mm3 * invn);
        }
    }
}

extern "C" void kernel_launch(void* const* d_in, const int* in_sizes, int n_in,
                              void* d_out, int out_size, void* d_ws, size_t ws_size,
                              hipStream_t stream)
{
    const float* x     = (const float*)d_in[0];
    const int*   src   = (const int*)d_in[1];
    const int*   dst   = (const int*)d_in[2];
    const int*   efeat = (const int*)d_in[3];
    const float* W1    = (const float*)d_in[4];
    const float* Eemb1 = (const float*)d_in[5];
    const float* We1   = (const float*)d_in[6];
    const float* al1   = (const float*)d_in[7];
    const float* ar1   = (const float*)d_in[8];
    const float* ae1   = (const float*)d_in[9];
    const float* W2    = (const float*)d_in[10];
    const float* Eemb2 = (const float*)d_in[11];
    const float* We2   = (const float*)d_in[12];
    const float* al2   = (const float*)d_in[13];
    const float* ar2   = (const float*)d_in[14];
    const float* ae2   = (const float*)d_in[15];
    const float* Wres2 = (const float*)d_in[16];

    char* w = (char*)d_ws;
    auto alloc = [&](size_t bytes) {
        char* p = w;
        w += (bytes + 255) & ~(size_t)255;
        return p;
    };
    ushort* featb = (ushort*)alloc((size_t)NN * FEAT * 2);   // gemm out (bf16)
    ushort* h1b   = (ushort*)alloc((size_t)NN * FEAT * 2);   // layer1 out (bf16)
    ushort* resb  = (ushort*)alloc((size_t)NN * FEAT * 2);   // residual (bf16)
    float4* el4   = (float4*)alloc((size_t)NN * 16);
    float4* er4   = (float4*)alloc((size_t)NN * 16);
    int*    deg   = (int*)alloc((size_t)NN * 4);
    int*    off   = (int*)alloc((size_t)(NN + 1) * 4);
    int*    cur   = (int*)alloc((size_t)NN * 4);
    int*    srcP  = (int*)alloc((size_t)EEN * 4);
    int*    bsum  = (int*)alloc(64 * 4);
    int*    bexc  = (int*)alloc(64 * 4);
    ushort* w1bt  = (ushort*)alloc((size_t)FEAT * INF_ * 2);
    ushort* w2bt  = (ushort*)alloc((size_t)FEAT * FEAT * 2);
    ushort* wrbt  = (ushort*)alloc((size_t)FEAT * FEAT * 2);
    float*  ee1   = (float*)alloc(24 * 4);
    float*  ee2   = (float*)alloc(24 * 4);

    hipMemsetAsync(deg, 0, (size_t)NN * 4, stream);

    const int eb = (EEN + 255) / 256;
    k_hist<<<eb, 256, 0, stream>>>(dst, deg);
    k_scan1<<<NB, 1024, 0, stream>>>(deg, off, bsum);
    k_scan2<<<1, 64, 0, stream>>>(bsum, bexc, off);
    k_scan3<<<NB, 1024, 0, stream>>>(off, cur, bexc);
    k_scatter<<<eb, 256, 0, stream>>>(src, dst, efeat, cur, srcP);
    k_eetab2<<<2, 192, 0, stream>>>(Eemb1, We1, ae1, ee1, Eemb2, We2, ae2, ee2);
    k_wtrans3<<<120, 256, 0, stream>>>(W1, w1bt, W2, w2bt, Wres2, wrbt);

    const int nb4 = (NN + 3) / 4;
    // ---- layer 1 ----
    gemm_mfma1<<<(NN + 127) / 128, 256, 0, stream>>>(x, w1bt, featb,
            el4, er4, al1, ar1, NN, INF_);
    k_attn_agg<false, false><<<nb4, 256, 0, stream>>>(off, srcP, el4, er4, ee1,
            featb, nullptr, h1b);
    // ---- layer 2 (W2 and Wres in one pass) ----
    gemm_mfma2<<<(NN + 63) / 64, 256, 0, stream>>>(h1b, w2bt, wrbt, featb,
            resb, el4, er4, al2, ar2, NN, FEAT);
    k_attn_agg<true, true><<<nb4, 256, 0, stream>>>(off, srcP, el4, er4, ee2,
            featb, resb, (float*)d_out);
}